// Round 15
// baseline (245.226 us; speedup 1.0000x reference)
//
#include <hip/hip_runtime.h>

// MPNN: edge MLP (131->128->64) + scatter-mean + node MLP (128->128->64)
// N=50000, E=800000, fp32 in/out.
// R15: overlap fill with pq. Chain: K1 pack U count(+rank)+aggr-zero ->
// K2 scan (lookback, alone, ~5us) -> K3 fill U pq (disjoint bottlenecks:
// random scatter vs MFMA streaming -> runtime ~= max not sum) -> K4 edge
// (R14's branchless-gather version, 63us) -> K5 node.
// Factorization (exact): hidden = relu(P[i]+Q[j]),
//   P = x@(W1a-W1b) - pos@W1c + b1,  Q = x@W1b + pos@W1c.

#define EPB 128  // edges per block (4 waves x M=32)
#define NPB 64   // nodes per block (4 waves x M=16)

typedef __attribute__((ext_vector_type(8))) short bf16x8;
typedef __attribute__((ext_vector_type(4))) float f32x4;

static __device__ __forceinline__ unsigned short f2bf(float f) {
    union { float f; unsigned u; } v; v.f = f;
    unsigned u = v.u + 0x7FFFu + ((v.u >> 16) & 1u);  // RNE
    return (unsigned short)(u >> 16);
}
static __device__ __forceinline__ float bf2f(unsigned short h) {
    union { unsigned u; float f; } v; v.u = ((unsigned)h) << 16;
    return v.f;
}
// packed: two bf16 in u32 -> relu(p+q) -> two bf16 (truncating round)
static __device__ __forceinline__ unsigned relu_add_pk(unsigned pu, unsigned qu) {
    union { unsigned u; float f; } plo, phi, qlo, qhi, lo, hi;
    plo.u = pu << 16;           phi.u = pu & 0xffff0000u;
    qlo.u = qu << 16;           qhi.u = qu & 0xffff0000u;
    lo.f = fmaxf(plo.f + qlo.f, 0.f);
    hi.f = fmaxf(phi.f + qhi.f, 0.f);
    return (hi.u & 0xffff0000u) | (lo.u >> 16);
}

// ---- K1: pack weights U count(+rank)+aggr-zero U bsum sentinels ----

__global__ __launch_bounds__(256) void prep_kernel(
    const float* __restrict__ W1, const float* __restrict__ W2,
    const float* __restrict__ W3, const float* __restrict__ W4,
    unsigned short* __restrict__ Wcp, unsigned short* __restrict__ W2p,
    unsigned short* __restrict__ W3p, unsigned short* __restrict__ W4p,
    const int* __restrict__ ei0, int* __restrict__ cnt,
    int* __restrict__ rank, int* __restrict__ bsum,
    float4* __restrict__ aggr4, int nAggr4, int E)
{
    const int tid = threadIdx.x;
    if (blockIdx.x < 28) {
        if (blockIdx.x == 0) bsum[tid] = -1;   // lookback sentinels (256 slots)
        int f = blockIdx.x * 4 + (tid >> 6);   // 0..111
        const int lane = tid & 63;
        if (f < 48) {
            const int nt = f / 3, ks = f % 3;
            const int n  = nt * 16 + (lane & 15);
            const int k0 = ks * 32 + (lane >> 4) * 8;
            unsigned short* dst = Wcp + (size_t)f * 512 + lane * 8;
            #pragma unroll
            for (int j = 0; j < 8; ++j) {
                const int k = k0 + j;
                float v = 0.f;
                if (n < 128) {          // P-part
                    if (k < 64)       v = W1[(size_t)k * 128 + n] - W1[(size_t)(64 + k) * 128 + n];
                    else if (k < 67)  v = -W1[(size_t)(128 + k - 64) * 128 + n];
                } else {                // Q-part
                    const int nq = n - 128;
                    if (k < 64)       v = W1[(size_t)(64 + k) * 128 + nq];
                    else if (k < 67)  v = W1[(size_t)(128 + k - 64) * 128 + nq];
                }
                dst[j] = f2bf(v);
            }
            return;
        }
        const float* W; unsigned short* out; int K, N, KS;
        if (f < 64)      { W = W2; out = W2p; K = 128; N = 64;  KS = 4; f -= 48; }
        else if (f < 96) { W = W3; out = W3p; K = 128; N = 128; KS = 4; f -= 64; }
        else             { W = W4; out = W4p; K = 128; N = 64;  KS = 4; f -= 96; }
        const int nt = f / KS, ks = f % KS;
        const int n  = nt * 16 + (lane & 15);
        const int k0 = ks * 32 + (lane >> 4) * 8;
        unsigned short* dst = out + (size_t)f * 512 + lane * 8;
        #pragma unroll
        for (int j = 0; j < 8; ++j) {
            float v = (k0 + j < K) ? W[(size_t)(k0 + j) * N + n] : 0.f;
            dst[j] = f2bf(v);
        }
    } else {
        const int e = (blockIdx.x - 28) * 256 + tid;
        if (e < nAggr4) aggr4[e] = make_float4(0.f, 0.f, 0.f, 0.f);
        if (e < E) rank[e] = atomicAdd(&cnt[ei0[e]], 1);
    }
}

// ---------------- K2: decoupled-lookback exclusive scan (alone) --------------

__global__ __launch_bounds__(256) void scan_kernel(
    const int* __restrict__ cnt, int* __restrict__ bsum,
    int* __restrict__ off, int N, int Etot)
{
    __shared__ int wsum[4];
    __shared__ int s_boff;

    const int tid  = threadIdx.x;
    const int s_id = blockIdx.x;
    const int scanBlocks = (N + 255) >> 8;
    const int i = s_id * 256 + tid;
    const int lane = tid & 63, w = tid >> 6;
    const int v = (i < N) ? cnt[i] : 0;
    int incl = v;
    #pragma unroll
    for (int d = 1; d < 64; d <<= 1) {
        int t = __shfl_up(incl, d, 64);
        if (lane >= d) incl += t;
    }
    if (lane == 63) wsum[w] = incl;
    if (tid == 0) s_boff = 0;
    __syncthreads();
    int pre = 0;
    for (int k = 0; k < w; ++k) pre += wsum[k];
    const int btot = wsum[0] + wsum[1] + wsum[2] + wsum[3];
    if (tid == 0) atomicExch(&bsum[s_id], btot);    // publish (device scope)
    if (tid < s_id) {                               // one predecessor/thread
        int val;
        do {
            val = __hip_atomic_load(&bsum[tid], __ATOMIC_RELAXED,
                                    __HIP_MEMORY_SCOPE_AGENT);
        } while (val == -1);
        atomicAdd(&s_boff, val);                    // LDS atomic
    }
    __syncthreads();
    if (i < N) off[i] = s_boff + pre + incl - v;
    if (s_id == scanBlocks - 1 && tid == 0) off[N] = Etot;
}

// ---------------- K3: fill (random scatter) U pq (MFMA projection) ----------
// blocks [0, fillBlocks): fill; blocks [fillBlocks, +pqBlocks): pq.
// Disjoint bottlenecks -> concurrent execution ~= max(fill, pq).

__global__ __launch_bounds__(256) void fill_pq_kernel(
    const int* __restrict__ ei0, const int* __restrict__ ei1,
    const int* __restrict__ off, const int* __restrict__ rank,
    unsigned* __restrict__ eij,
    const float* __restrict__ x, const float* __restrict__ pos,
    const unsigned short* __restrict__ Wcp, const float* __restrict__ b1,
    unsigned short* __restrict__ P, unsigned short* __restrict__ Q,
    int N, int E, int fillBlocks)
{
    __shared__ unsigned short s[NPB][136];

    const int tid = threadIdx.x;

    if ((int)blockIdx.x < fillBlocks) {
        // ---- fill: atomic-free CSR permute (packed u32)
        int e = blockIdx.x * 256 + tid;
        if (e < E) {
            const int i = ei0[e];
            eij[off[i] + rank[e]] = ((unsigned)i << 16) | (unsigned)ei1[e];
        }
        return;
    }

    // ---- pq part
    const int wv   = tid >> 6;
    const int lane = tid & 63;
    const int r    = lane >> 4;
    const int c    = lane & 15;
    const int base = (blockIdx.x - fillBlocks) * NPB;

    for (int nl = wv; nl < NPB; nl += 4) {
        const int n = base + nl;
        s[nl][lane] = (n < N) ? f2bf(x[(size_t)n * 64 + lane]) : 0;
        if (lane < 32)
            s[nl][64 + lane] = (n < N && lane < 3) ? f2bf(pos[(size_t)n * 3 + lane]) : 0;
    }
    __syncthreads();

    bf16x8 a[3];
    #pragma unroll
    for (int ks = 0; ks < 3; ++ks)
        a[ks] = *(const bf16x8*)&s[wv * 16 + c][ks * 32 + r * 8];
    __syncthreads();   // all frag reads done before staging overwrites s

    f32x4 acc[16];
    #pragma unroll
    for (int nt = 0; nt < 16; ++nt) {
        const float bv = (nt < 8) ? b1[nt * 16 + c] : 0.f;  // bias folded into P
        acc[nt] = (f32x4){bv, bv, bv, bv};
    }
    #pragma unroll
    for (int nt = 0; nt < 16; ++nt)
        #pragma unroll
        for (int ks = 0; ks < 3; ++ks) {
            const bf16x8 b = *(const bf16x8*)(Wcp + (size_t)(nt * 3 + ks) * 512 + lane * 8);
            acc[nt] = __builtin_amdgcn_mfma_f32_16x16x32_bf16(a[ks], b, acc[nt], 0, 0, 0);
        }

    // ---- stage P rows in LDS, coalesced ushort4 store (32 ushort4/row)
    #pragma unroll
    for (int nt = 0; nt < 8; ++nt)
        #pragma unroll
        for (int reg = 0; reg < 4; ++reg)
            s[wv * 16 + r * 4 + reg][nt * 16 + c] = f2bf(acc[nt][reg]);
    __syncthreads();
    {
        const int nl = tid >> 2, q = tid & 3;
        const int n = base + nl;
        if (n < N) {
            const ushort4* src = (const ushort4*)&s[nl][0];
            ushort4* dst = (ushort4*)(P + (size_t)n * 128);
            #pragma unroll
            for (int u = 0; u < 8; ++u) dst[q * 8 + u] = src[q * 8 + u];
        }
    }
    __syncthreads();

    // ---- stage Q rows, same path
    #pragma unroll
    for (int nt = 8; nt < 16; ++nt)
        #pragma unroll
        for (int reg = 0; reg < 4; ++reg)
            s[wv * 16 + r * 4 + reg][(nt - 8) * 16 + c] = f2bf(acc[nt][reg]);
    __syncthreads();
    {
        const int nl = tid >> 2, q = tid & 3;
        const int n = base + nl;
        if (n < N) {
            const ushort4* src = (const ushort4*)&s[nl][0];
            ushort4* dst = (ushort4*)(Q + (size_t)n * 128);
            #pragma unroll
            for (int u = 0; u < 8; ++u) dst[q * 8 + u] = src[q * 8 + u];
        }
    }
}

// ------- K4: relu(P[i]+Q[j]) -> layer-2 MFMA -> fused seg-reduce ----
// 256 threads, 4 waves x M=32 = 128 edges/block; branchless frag build.

__global__ __launch_bounds__(256) void edge_aggr_mfma(
    const unsigned short* __restrict__ P, const unsigned short* __restrict__ Q,
    const unsigned* __restrict__ eij,
    const unsigned short* __restrict__ W2p, const float* __restrict__ b2,
    float* __restrict__ aggr, int E)
{
    __shared__ unsigned short s_m[EPB][72];  // msgs, 64 cols + 8 pad
    __shared__ unsigned s_ij[EPB];           // packed (i<<16)|j
    __shared__ int  s_start[EPB + 4];        // run starts + terminator
    __shared__ int  s_wsumA[2];
    __shared__ int  s_nruns;

    const int tid  = threadIdx.x;
    const int wv   = tid >> 6;
    const int lane = tid & 63;
    const int r    = lane >> 4;
    const int c    = lane & 15;

    // XCD-contiguous swizzle: grid padded to x8
    const int per  = gridDim.x >> 3;
    const int swz  = (blockIdx.x & 7) * per + (blockIdx.x >> 3);
    const int base = swz * EPB;
    if (base >= E) return;
    const int ne   = min(EPB, E - base);     // valid slots in this block (>=1)

    if (tid < EPB) {
        const int p = base + tid;
        s_ij[tid] = eij[min(p, E - 1)];      // clamped: pad slots hold valid (i,j)
    }
    __syncthreads();

    // ---- layer-2 A-frags: relu(P[i]+Q[j]) via packed-dword unpack/add/trunc
    bf16x8 a2[2][4];
    #pragma unroll
    for (int mh = 0; mh < 2; ++mh) {
        const unsigned ij = s_ij[wv * 32 + mh * 16 + c];
        const unsigned* Pi = (const unsigned*)(P + (size_t)(ij >> 16) * 128);
        const unsigned* Qj = (const unsigned*)(Q + (size_t)(ij & 0xFFFFu) * 128);
        #pragma unroll
        for (int ks = 0; ks < 4; ++ks) {
            const uint4 pu = *(const uint4*)(Pi + ks * 16 + r * 4);
            const uint4 qu = *(const uint4*)(Qj + ks * 16 + r * 4);
            uint4 h;
            h.x = relu_add_pk(pu.x, qu.x);
            h.y = relu_add_pk(pu.y, qu.y);
            h.z = relu_add_pk(pu.z, qu.z);
            h.w = relu_add_pk(pu.w, qu.w);
            a2[mh][ks] = *(const bf16x8*)&h;
        }
    }

    // ---- layer 2: msg = hidden @ W2 + b2, N=64, K=128
    f32x4 acc2[2][4];
    #pragma unroll
    for (int nt = 0; nt < 4; ++nt) {
        const float bv = b2[nt * 16 + c];
        acc2[0][nt] = (f32x4){bv, bv, bv, bv};
        acc2[1][nt] = (f32x4){bv, bv, bv, bv};
    }
    #pragma unroll
    for (int nt = 0; nt < 4; ++nt)
        #pragma unroll
        for (int ks = 0; ks < 4; ++ks) {
            const bf16x8 b = *(const bf16x8*)(W2p + (size_t)(nt * 4 + ks) * 512 + lane * 8);
            acc2[0][nt] = __builtin_amdgcn_mfma_f32_16x16x32_bf16(a2[0][ks], b, acc2[0][nt], 0, 0, 0);
            acc2[1][nt] = __builtin_amdgcn_mfma_f32_16x16x32_bf16(a2[1][ks], b, acc2[1][nt], 0, 0, 0);
        }

    // ---- msgs to LDS (bf16, RNE)
    #pragma unroll
    for (int mh = 0; mh < 2; ++mh)
        #pragma unroll
        for (int nt = 0; nt < 4; ++nt)
            #pragma unroll
            for (int reg = 0; reg < 4; ++reg) {
                const int row = wv * 32 + mh * 16 + r * 4 + reg;
                s_m[row][nt * 16 + c] = f2bf(acc2[mh][nt][reg]);
            }

    // ---- run detection over slots [0, ne): compare high-16 (i field)
    int flag = 0, incl = 0;
    if (tid < EPB) {
        flag = (tid < ne) &&
               (tid == 0 || (s_ij[tid] >> 16) != (s_ij[tid - 1] >> 16));
        incl = flag;
    }
    #pragma unroll
    for (int d = 1; d < 64; d <<= 1) {
        int t = __shfl_up(incl, d, 64);
        if (lane >= d) incl += t;
    }
    if (tid < EPB && lane == 63) s_wsumA[tid >> 6] = incl;
    __syncthreads();                         // also covers s_m writes above
    if (tid < EPB) {
        const int rid = incl + ((tid >= 64) ? s_wsumA[0] : 0);
        if (flag) s_start[rid - 1] = tid;
    }
    if (tid == 0) {
        const int nr = s_wsumA[0] + s_wsumA[1];
        s_nruns = nr;
        s_start[nr] = ne;
    }
    __syncthreads();

    // ---- segmented reduce: one wave per run, lanes = 64 cols
    for (int rn = wv; rn < s_nruns; rn += 4) {
        const int e0 = s_start[rn], e1 = s_start[rn + 1];
        const int i  = (int)(s_ij[e0] >> 16);
        float acc = 0.f;
        for (int e = e0; e < e1; ++e)
            acc += bf2f(s_m[e][lane]);
        atomicAdd(&aggr[(size_t)i * 64 + lane], acc);
    }
}

// ---------------- K5: node MLP (streaming aggr) ----------------

__global__ __launch_bounds__(256) void node_mlp_mfma(
    const float* __restrict__ x, const float* __restrict__ aggr,
    const int* __restrict__ off,
    const unsigned short* __restrict__ W3p, const float* __restrict__ b3,
    const unsigned short* __restrict__ W4p, const float* __restrict__ b4,
    float* __restrict__ out, int N)
{
    __shared__ unsigned short s_a[NPB][136];  // 128 + 8 pad

    const int tid  = threadIdx.x;
    const int wv   = tid >> 6;
    const int lane = tid & 63;
    const int r    = lane >> 4;
    const int c    = lane & 15;
    const int base = blockIdx.x * NPB;

    for (int nl = wv; nl < NPB; nl += 4) {
        const int n = base + nl;
        if (n < N) {
            s_a[nl][lane] = f2bf(x[(size_t)n * 64 + lane]);
            const int deg = off[n + 1] - off[n];
            const float a = aggr[(size_t)n * 64 + lane] / (float)max(deg, 1);
            s_a[nl][64 + lane] = f2bf(a);
        } else {
            s_a[nl][lane] = 0;
            s_a[nl][64 + lane] = 0;
        }
    }
    __syncthreads();

    bf16x8 a1[4];
    #pragma unroll
    for (int ks = 0; ks < 4; ++ks)
        a1[ks] = *(const bf16x8*)&s_a[wv * 16 + c][ks * 32 + r * 8];
    __syncthreads();

    f32x4 acc1[8];
    #pragma unroll
    for (int nt = 0; nt < 8; ++nt) {
        const float bv = b3[nt * 16 + c];
        acc1[nt] = (f32x4){bv, bv, bv, bv};
    }
    #pragma unroll
    for (int nt = 0; nt < 8; ++nt)
        #pragma unroll
        for (int ks = 0; ks < 4; ++ks) {
            const bf16x8 b = *(const bf16x8*)(W3p + (size_t)(nt * 4 + ks) * 512 + lane * 8);
            acc1[nt] = __builtin_amdgcn_mfma_f32_16x16x32_bf16(a1[ks], b, acc1[nt], 0, 0, 0);
        }
    #pragma unroll
    for (int nt = 0; nt < 8; ++nt)
        #pragma unroll
        for (int reg = 0; reg < 4; ++reg)
            s_a[wv * 16 + r * 4 + reg][nt * 16 + c] = f2bf(fmaxf(acc1[nt][reg], 0.f));
    __syncthreads();

    bf16x8 a2[4];
    #pragma unroll
    for (int ks = 0; ks < 4; ++ks)
        a2[ks] = *(const bf16x8*)&s_a[wv * 16 + c][ks * 32 + r * 8];
    __syncthreads();

    f32x4 acc2[4];
    #pragma unroll
    for (int nt = 0; nt < 4; ++nt) {
        const float bv = b4[nt * 16 + c];
        acc2[nt] = (f32x4){bv, bv, bv, bv};
    }
    #pragma unroll
    for (int nt = 0; nt < 4; ++nt)
        #pragma unroll
        for (int ks = 0; ks < 4; ++ks) {
            const bf16x8 b = *(const bf16x8*)(W4p + (size_t)(nt * 4 + ks) * 512 + lane * 8);
            acc2[nt] = __builtin_amdgcn_mfma_f32_16x16x32_bf16(a2[ks], b, acc2[nt], 0, 0, 0);
        }

    #pragma unroll
    for (int nt = 0; nt < 4; ++nt)
        #pragma unroll
        for (int reg = 0; reg < 4; ++reg) {
            float* row = (float*)&s_a[wv * 16 + r * 4 + reg][0];
            row[nt * 16 + c] = acc2[nt][reg];
        }
    __syncthreads();

    {
        const int nl = tid >> 2, q = tid & 3;
        const int n = base + nl;
        if (n < N) {
            const float4* src = (const float4*)((const float*)&s_a[nl][0] + q * 16);
            float4* dst = (float4*)(out + (size_t)n * 64 + q * 16);
            #pragma unroll
            for (int u = 0; u < 4; ++u) dst[u] = src[u];
        }
    }
}

// ---------------- fallback (atomic fp32 path, if ws too small) ----------------

#define EB 32
#define NB 32

__global__ __launch_bounds__(256) void mpnn_edge_atomic_kernel(
    const float* __restrict__ x, const float* __restrict__ pos,
    const int* __restrict__ ei0, const int* __restrict__ ei1,
    const float* __restrict__ W1, const float* __restrict__ b1,
    const float* __restrict__ W2, const float* __restrict__ b2,
    float* __restrict__ summed, float* __restrict__ counts, int E)
{
    __shared__ float s_in[EB][132];
    __shared__ int   s_idx[EB];

    const int tid  = threadIdx.x;
    const int base = blockIdx.x * EB;
    const int wv   = tid >> 6;
    const int lane = tid & 63;

    for (int e = wv; e < EB; e += 4) {
        const int ei = base + e;
        if (ei < E) {
            const int i = ei0[ei];
            const int j = ei1[ei];
            const float xi = x[(size_t)i * 64 + lane];
            const float xj = x[(size_t)j * 64 + lane];
            s_in[e][lane]      = xi;
            s_in[e][64 + lane] = xj - xi;
            if (lane < 3)
                s_in[e][128 + lane] = pos[(size_t)j * 3 + lane] - pos[(size_t)i * 3 + lane];
            if (lane == 0) s_idx[e] = i;
        } else {
            s_in[e][lane] = 0.f; s_in[e][64 + lane] = 0.f;
            if (lane < 3) s_in[e][128 + lane] = 0.f;
            if (lane == 0) s_idx[e] = -1;
        }
    }
    __syncthreads();

    float acc1[4][4];
    {
        const int cg = tid & 31;
        const int er = tid >> 5;
        const float4 bb = *(const float4*)(b1 + 4 * cg);
        #pragma unroll
        for (int t = 0; t < 4; ++t) {
            acc1[t][0] = bb.x; acc1[t][1] = bb.y; acc1[t][2] = bb.z; acc1[t][3] = bb.w;
        }
        for (int k = 0; k < 128; k += 4) {
            float wv4[4][4];
            #pragma unroll
            for (int kk = 0; kk < 4; ++kk) {
                const float4 w = *(const float4*)(W1 + (size_t)(k + kk) * 128 + 4 * cg);
                wv4[kk][0] = w.x; wv4[kk][1] = w.y; wv4[kk][2] = w.z; wv4[kk][3] = w.w;
            }
            #pragma unroll
            for (int t = 0; t < 4; ++t) {
                const float4 m = *(const float4*)(&s_in[er + 8 * t][k]);
                const float mm[4] = {m.x, m.y, m.z, m.w};
                #pragma unroll
                for (int kk = 0; kk < 4; ++kk)
                    #pragma unroll
                    for (int cc = 0; cc < 4; ++cc)
                        acc1[t][cc] += mm[kk] * wv4[kk][cc];
            }
        }
        for (int k = 128; k < 131; ++k) {
            float wk[4];
            #pragma unroll
            for (int cc = 0; cc < 4; ++cc) wk[cc] = W1[(size_t)k * 128 + 4 * cg + cc];
            #pragma unroll
            for (int t = 0; t < 4; ++t) {
                const float m = s_in[er + 8 * t][k];
                #pragma unroll
                for (int cc = 0; cc < 4; ++cc) acc1[t][cc] += m * wk[cc];
            }
        }
    }
    __syncthreads();
    {
        const int cg = tid & 31;
        const int er = tid >> 5;
        #pragma unroll
        for (int t = 0; t < 4; ++t)
            #pragma unroll
            for (int cc = 0; cc < 4; ++cc)
                s_in[er + 8 * t][4 * cg + cc] = fmaxf(acc1[t][cc], 0.f);
    }
    __syncthreads();
    {
        const int cg = tid & 15;
        const int er = tid >> 4;
        float acc[2][4];
        const float4 bb = *(const float4*)(b2 + 4 * cg);
        #pragma unroll
        for (int t = 0; t < 2; ++t) {
            acc[t][0] = bb.x; acc[t][1] = bb.y; acc[t][2] = bb.z; acc[t][3] = bb.w;
        }
        for (int k = 0; k < 128; k += 4) {
            float wv4[4][4];
            #pragma unroll
            for (int kk = 0; kk < 4; ++kk) {
                const float4 w = *(const float4*)(W2 + (size_t)(k + kk) * 64 + 4 * cg);
                wv4[kk][0] = w.x; wv4[kk][1] = w.y; wv4[kk][2] = w.z; wv4[kk][3] = w.w;
            }
            #pragma unroll
            for (int t = 0; t < 2; ++t) {
                const float4 m = *(const float4*)(&s_in[er + 16 * t][k]);
                const float mm[4] = {m.x, m.y, m.z, m.w};
                #pragma unroll
                for (int kk = 0; kk < 4; ++kk)
                    #pragma unroll
                    for (int cc = 0; cc < 4; ++cc)
                        acc[t][cc] += mm[kk] * wv4[kk][cc];
            }
        }
        #pragma unroll
        for (int t = 0; t < 2; ++t) {
            const int e = er + 16 * t;
            const int i = s_idx[e];
            if (i >= 0) {
                #pragma unroll
                for (int cc = 0; cc < 4; ++cc)
                    atomicAdd(&summed[(size_t)i * 64 + 4 * cg + cc], acc[t][cc]);
            }
        }
    }
    if (tid < EB) {
        const int i = s_idx[tid];
        if (i >= 0) atomicAdd(&counts[i], 1.0f);
    }
}

__global__ __launch_bounds__(256) void mpnn_node_legacy_kernel(
    const float* __restrict__ x, const float* __restrict__ summed,
    const float* __restrict__ counts,
    const float* __restrict__ W3, const float* __restrict__ b3,
    const float* __restrict__ W4, const float* __restrict__ b4,
    float* __restrict__ out, int N)
{
    __shared__ float s_in[NB][132];

    const int tid  = threadIdx.x;
    const int base = blockIdx.x * NB;
    const int wv   = tid >> 6;
    const int lane = tid & 63;

    for (int nl = wv; nl < NB; nl += 4) {
        const int n = base + nl;
        if (n < N) {
            s_in[nl][lane] = x[(size_t)n * 64 + lane];
            const float inv = 1.0f / fmaxf(counts[n], 1.0f);
            s_in[nl][64 + lane] = summed[(size_t)n * 64 + lane] * inv;
        } else {
            s_in[nl][lane] = 0.f; s_in[nl][64 + lane] = 0.f;
        }
    }
    __syncthreads();

    float acc1[4][4];
    {
        const int cg = tid & 31;
        const int er = tid >> 5;
        const float4 bb = *(const float4*)(b3 + 4 * cg);
        #pragma unroll
        for (int t = 0; t < 4; ++t) {
            acc1[t][0] = bb.x; acc1[t][1] = bb.y; acc1[t][2] = bb.z; acc1[t][3] = bb.w;
        }
        for (int k = 0; k < 128; k += 4) {
            float wv4[4][4];
            #pragma unroll
            for (int kk = 0; kk < 4; ++kk) {
                const float4 w = *(const float4*)(W3 + (size_t)(k + kk) * 128 + 4 * cg);
                wv4[kk][0] = w.x; wv4[kk][1] = w.y; wv4[kk][2] = w.z; wv4[kk][3] = w.w;
            }
            #pragma unroll
            for (int t = 0; t < 4; ++t) {
                const float4 m = *(const float4*)(&s_in[er + 8 * t][k]);
                const float mm[4] = {m.x, m.y, m.z, m.w};
                #pragma unroll
                for (int kk = 0; kk < 4; ++kk)
                    #pragma unroll
                    for (int cc = 0; cc < 4; ++cc)
                        acc1[t][cc] += mm[kk] * wv4[kk][cc];
            }
        }
    }
    __syncthreads();
    {
        const int cg = tid & 31;
        const int er = tid >> 5;
        #pragma unroll
        for (int t = 0; t < 4; ++t)
            #pragma unroll
            for (int cc = 0; cc < 4; ++cc)
                s_in[er + 8 * t][4 * cg + cc] = fmaxf(acc1[t][cc], 0.f);
    }
    __syncthreads();
    {
        const int cg = tid & 15;
        const int er = tid >> 4;
        float acc[2][4];
        const float4 bb = *(const float4*)(b4 + 4 * cg);
        #pragma unroll
        for (int t = 0; t < 2; ++t) {
            acc[t][0] = bb.x; acc[t][1] = bb.y; acc[t][2] = bb.z; acc[t][3] = bb.w;
        }
        for (int k = 0; k < 128; k += 4) {
            float wv4[4][4];
            #pragma unroll
            for (int kk = 0; kk < 4; ++kk) {
                const float4 w = *(const float4*)(W4 + (size_t)(k + kk) * 64 + 4 * cg);
                wv4[kk][0] = w.x; wv4[kk][1] = w.y; wv4[kk][2] = w.z; wv4[kk][3] = w.w;
            }
            #pragma unroll
            for (int t = 0; t < 2; ++t) {
                const float4 m = *(const float4*)(&s_in[er + 16 * t][k]);
                const float mm[4] = {m.x, m.y, m.z, m.w};
                #pragma unroll
                for (int kk = 0; kk < 4; ++kk)
                    #pragma unroll
                    for (int cc = 0; cc < 4; ++cc)
                        acc[t][cc] += mm[kk] * wv4[kk][cc];
            }
        }
        #pragma unroll
        for (int t = 0; t < 2; ++t) {
            const int n = base + er + 16 * t;
            if (n < N) {
                float4 o;
                o.x = acc[t][0]; o.y = acc[t][1]; o.z = acc[t][2]; o.w = acc[t][3];
                *(float4*)(out + (size_t)n * 64 + 4 * cg) = o;
            }
        }
    }
}

// ---------------- launch ----------------

static inline size_t rup(size_t v) { return (v + 255) & ~(size_t)255; }

extern "C" void kernel_launch(void* const* d_in, const int* in_sizes, int n_in,
                              void* d_out, int out_size, void* d_ws, size_t ws_size,
                              hipStream_t stream) {
    const float* x    = (const float*)d_in[0];
    const float* pos  = (const float*)d_in[1];
    const int*   eidx = (const int*)d_in[2];
    const float* W1   = (const float*)d_in[3];
    const float* b1   = (const float*)d_in[4];
    const float* W2   = (const float*)d_in[5];
    const float* b2   = (const float*)d_in[6];
    const float* W3   = (const float*)d_in[7];
    const float* b3   = (const float*)d_in[8];
    const float* W4   = (const float*)d_in[9];
    const float* b4   = (const float*)d_in[10];

    const int N = in_sizes[0] / 64;
    const int E = in_sizes[2] / 2;
    const int* ei0 = eidx;       // edge_index[0] = aggregation node i
    const int* ei1 = eidx + E;   // edge_index[1] = neighbor j

    const size_t p_b    = rup((size_t)N * 128 * 2);
    const size_t q_b    = rup((size_t)N * 128 * 2);
    const size_t wcp_b  = rup(48 * 512 * 2);
    const size_t w2p_b  = rup(16 * 512 * 2);
    const size_t w3p_b  = rup(32 * 512 * 2);
    const size_t w4p_b  = rup(16 * 512 * 2);
    const size_t aggr_b = rup((size_t)N * 64 * 4);
    const size_t cnt_b  = rup((size_t)N * 4);
    const size_t off_b  = rup((size_t)(N + 1) * 4);
    const size_t bsum_b = rup(256 * 4);
    const size_t rank_b = rup((size_t)E * 4);
    const size_t eij_b  = rup((size_t)E * 4);   // packed u32
    const size_t need = p_b + q_b + wcp_b + w2p_b + w3p_b + w4p_b +
                        aggr_b + cnt_b + off_b + bsum_b + rank_b + eij_b;

    if (ws_size >= need && N < 65536) {
        char* p = (char*)d_ws;
        unsigned short* P   = (unsigned short*)p;  p += p_b;
        unsigned short* Q   = (unsigned short*)p;  p += q_b;
        unsigned short* Wcp = (unsigned short*)p;  p += wcp_b;
        unsigned short* W2p = (unsigned short*)p;  p += w2p_b;
        unsigned short* W3p = (unsigned short*)p;  p += w3p_b;
        unsigned short* W4p = (unsigned short*)p;  p += w4p_b;
        float* aggr = (float*)p;  p += aggr_b;
        int* cnt  = (int*)p;  p += cnt_b;
        int* off  = (int*)p;  p += off_b;
        int* bsum = (int*)p;  p += bsum_b;
        int* rank = (int*)p;  p += rank_b;
        unsigned* eij = (unsigned*)p;

        hipMemsetAsync(cnt, 0, cnt_b, stream);  // aggr zeroed inside prep

        // K1: pack (28 blocks) U count+aggr-zero U bsum sentinels
        const int zN = N * 16;                  // aggr float4 count
        const int workMax = (E > zN) ? E : zN;
        const int cntBlocks = (workMax + 255) / 256;
        prep_kernel<<<28 + cntBlocks, 256, 0, stream>>>(
            W1, W2, W3, W4, Wcp, W2p, W3p, W4p, ei0, cnt, rank, bsum,
            (float4*)aggr, zN, E);

        // K2: lookback scan (alone; 196 blocks, co-resident)
        const int scanBlocks = (N + 255) / 256;
        scan_kernel<<<scanBlocks, 256, 0, stream>>>(cnt, bsum, off, N, E);

        // K3: fill (3125 blocks, first) U pq (782 blocks)
        const int fillBlocks = (E + 255) / 256;
        const int pqBlocks   = (N + NPB - 1) / NPB;
        fill_pq_kernel<<<fillBlocks + pqBlocks, 256, 0, stream>>>(
            ei0, ei1, off, rank, eij, x, pos, Wcp, b1, P, Q, N, E, fillBlocks);

        // K4: edge (256 threads, grid padded to x8 for XCD-contiguous swizzle)
        const int edgeBlocks = ((E + EPB - 1) / EPB + 7) & ~7;
        edge_aggr_mfma<<<edgeBlocks, 256, 0, stream>>>(
            P, Q, eij, W2p, b2, aggr, E);

        // K5: node
        node_mlp_mfma<<<pqBlocks, 256, 0, stream>>>(
            x, aggr, off, W3p, b3, W4p, b4, (float*)d_out, N);
    } else {
        // fallback: atomic fp32 path
        float* summed = (float*)d_ws;
        float* counts = summed + (size_t)N * 64;
        hipMemsetAsync(d_ws, 0, ((size_t)N * 64 + N) * sizeof(float), stream);

        mpnn_edge_atomic_kernel<<<(E + EB - 1) / EB, 256, 0, stream>>>(
            x, pos, ei0, ei1, W1, b1, W2, b2, summed, counts, E);
        mpnn_node_legacy_kernel<<<(N + NB - 1) / NB, 256, 0, stream>>>(
            x, summed, counts, W3, b3, W4, b4, (float*)d_out, N);
    }
}

// Round 16
// 244.334 us; speedup vs baseline: 1.0037x; 1.0037x over previous
//
#include <hip/hip_runtime.h>

// MPNN: edge MLP (131->128->64) + scatter-mean + node MLP (128->128->64)
// N=50000, E=800000, fp32 in/out.
// R16: R15 with aggr-zeroing reverted to hipMemsetAsync (R14 ledger showed
// absorbing the 12.8MB zero into prep's count pass cost ~+6us; memset was
// ~3us at R11). aggr and cnt adjacent -> single memset.
// Chain: memset -> K1 pack U count(+rank) -> K2 scan -> K3 fill U pq ->
// K4 edge (branchless gather, 63us) -> K5 node.
// Factorization (exact): hidden = relu(P[i]+Q[j]),
//   P = x@(W1a-W1b) - pos@W1c + b1,  Q = x@W1b + pos@W1c.

#define EPB 128  // edges per block (4 waves x M=32)
#define NPB 64   // nodes per block (4 waves x M=16)

typedef __attribute__((ext_vector_type(8))) short bf16x8;
typedef __attribute__((ext_vector_type(4))) float f32x4;

static __device__ __forceinline__ unsigned short f2bf(float f) {
    union { float f; unsigned u; } v; v.f = f;
    unsigned u = v.u + 0x7FFFu + ((v.u >> 16) & 1u);  // RNE
    return (unsigned short)(u >> 16);
}
static __device__ __forceinline__ float bf2f(unsigned short h) {
    union { unsigned u; float f; } v; v.u = ((unsigned)h) << 16;
    return v.f;
}
// packed: two bf16 in u32 -> relu(p+q) -> two bf16 (truncating round)
static __device__ __forceinline__ unsigned relu_add_pk(unsigned pu, unsigned qu) {
    union { unsigned u; float f; } plo, phi, qlo, qhi, lo, hi;
    plo.u = pu << 16;           phi.u = pu & 0xffff0000u;
    qlo.u = qu << 16;           qhi.u = qu & 0xffff0000u;
    lo.f = fmaxf(plo.f + qlo.f, 0.f);
    hi.f = fmaxf(phi.f + qhi.f, 0.f);
    return (hi.u & 0xffff0000u) | (lo.u >> 16);
}

// ---- K1: pack weights U count(+rank) U bsum sentinels ----

__global__ __launch_bounds__(256) void prep_kernel(
    const float* __restrict__ W1, const float* __restrict__ W2,
    const float* __restrict__ W3, const float* __restrict__ W4,
    unsigned short* __restrict__ Wcp, unsigned short* __restrict__ W2p,
    unsigned short* __restrict__ W3p, unsigned short* __restrict__ W4p,
    const int* __restrict__ ei0, int* __restrict__ cnt,
    int* __restrict__ rank, int* __restrict__ bsum, int E)
{
    const int tid = threadIdx.x;
    if (blockIdx.x < 28) {
        if (blockIdx.x == 0) bsum[tid] = -1;   // lookback sentinels (256 slots)
        int f = blockIdx.x * 4 + (tid >> 6);   // 0..111
        const int lane = tid & 63;
        if (f < 48) {
            const int nt = f / 3, ks = f % 3;
            const int n  = nt * 16 + (lane & 15);
            const int k0 = ks * 32 + (lane >> 4) * 8;
            unsigned short* dst = Wcp + (size_t)f * 512 + lane * 8;
            #pragma unroll
            for (int j = 0; j < 8; ++j) {
                const int k = k0 + j;
                float v = 0.f;
                if (n < 128) {          // P-part
                    if (k < 64)       v = W1[(size_t)k * 128 + n] - W1[(size_t)(64 + k) * 128 + n];
                    else if (k < 67)  v = -W1[(size_t)(128 + k - 64) * 128 + n];
                } else {                // Q-part
                    const int nq = n - 128;
                    if (k < 64)       v = W1[(size_t)(64 + k) * 128 + nq];
                    else if (k < 67)  v = W1[(size_t)(128 + k - 64) * 128 + nq];
                }
                dst[j] = f2bf(v);
            }
            return;
        }
        const float* W; unsigned short* out; int K, N, KS;
        if (f < 64)      { W = W2; out = W2p; K = 128; N = 64;  KS = 4; f -= 48; }
        else if (f < 96) { W = W3; out = W3p; K = 128; N = 128; KS = 4; f -= 64; }
        else             { W = W4; out = W4p; K = 128; N = 64;  KS = 4; f -= 96; }
        const int nt = f / KS, ks = f % KS;
        const int n  = nt * 16 + (lane & 15);
        const int k0 = ks * 32 + (lane >> 4) * 8;
        unsigned short* dst = out + (size_t)f * 512 + lane * 8;
        #pragma unroll
        for (int j = 0; j < 8; ++j) {
            float v = (k0 + j < K) ? W[(size_t)(k0 + j) * N + n] : 0.f;
            dst[j] = f2bf(v);
        }
    } else {
        const int e = (blockIdx.x - 28) * 256 + tid;
        if (e < E) rank[e] = atomicAdd(&cnt[ei0[e]], 1);
    }
}

// ---------------- K2: decoupled-lookback exclusive scan (alone) --------------

__global__ __launch_bounds__(256) void scan_kernel(
    const int* __restrict__ cnt, int* __restrict__ bsum,
    int* __restrict__ off, int N, int Etot)
{
    __shared__ int wsum[4];
    __shared__ int s_boff;

    const int tid  = threadIdx.x;
    const int s_id = blockIdx.x;
    const int scanBlocks = (N + 255) >> 8;
    const int i = s_id * 256 + tid;
    const int lane = tid & 63, w = tid >> 6;
    const int v = (i < N) ? cnt[i] : 0;
    int incl = v;
    #pragma unroll
    for (int d = 1; d < 64; d <<= 1) {
        int t = __shfl_up(incl, d, 64);
        if (lane >= d) incl += t;
    }
    if (lane == 63) wsum[w] = incl;
    if (tid == 0) s_boff = 0;
    __syncthreads();
    int pre = 0;
    for (int k = 0; k < w; ++k) pre += wsum[k];
    const int btot = wsum[0] + wsum[1] + wsum[2] + wsum[3];
    if (tid == 0) atomicExch(&bsum[s_id], btot);    // publish (device scope)
    if (tid < s_id) {                               // one predecessor/thread
        int val;
        do {
            val = __hip_atomic_load(&bsum[tid], __ATOMIC_RELAXED,
                                    __HIP_MEMORY_SCOPE_AGENT);
        } while (val == -1);
        atomicAdd(&s_boff, val);                    // LDS atomic
    }
    __syncthreads();
    if (i < N) off[i] = s_boff + pre + incl - v;
    if (s_id == scanBlocks - 1 && tid == 0) off[N] = Etot;
}

// ---------------- K3: fill (random scatter) U pq (MFMA projection) ----------

__global__ __launch_bounds__(256) void fill_pq_kernel(
    const int* __restrict__ ei0, const int* __restrict__ ei1,
    const int* __restrict__ off, const int* __restrict__ rank,
    unsigned* __restrict__ eij,
    const float* __restrict__ x, const float* __restrict__ pos,
    const unsigned short* __restrict__ Wcp, const float* __restrict__ b1,
    unsigned short* __restrict__ P, unsigned short* __restrict__ Q,
    int N, int E, int fillBlocks)
{
    __shared__ unsigned short s[NPB][136];

    const int tid = threadIdx.x;

    if ((int)blockIdx.x < fillBlocks) {
        // ---- fill: atomic-free CSR permute (packed u32)
        int e = blockIdx.x * 256 + tid;
        if (e < E) {
            const int i = ei0[e];
            eij[off[i] + rank[e]] = ((unsigned)i << 16) | (unsigned)ei1[e];
        }
        return;
    }

    // ---- pq part
    const int wv   = tid >> 6;
    const int lane = tid & 63;
    const int r    = lane >> 4;
    const int c    = lane & 15;
    const int base = (blockIdx.x - fillBlocks) * NPB;

    for (int nl = wv; nl < NPB; nl += 4) {
        const int n = base + nl;
        s[nl][lane] = (n < N) ? f2bf(x[(size_t)n * 64 + lane]) : 0;
        if (lane < 32)
            s[nl][64 + lane] = (n < N && lane < 3) ? f2bf(pos[(size_t)n * 3 + lane]) : 0;
    }
    __syncthreads();

    bf16x8 a[3];
    #pragma unroll
    for (int ks = 0; ks < 3; ++ks)
        a[ks] = *(const bf16x8*)&s[wv * 16 + c][ks * 32 + r * 8];
    __syncthreads();   // all frag reads done before staging overwrites s

    f32x4 acc[16];
    #pragma unroll
    for (int nt = 0; nt < 16; ++nt) {
        const float bv = (nt < 8) ? b1[nt * 16 + c] : 0.f;  // bias folded into P
        acc[nt] = (f32x4){bv, bv, bv, bv};
    }
    #pragma unroll
    for (int nt = 0; nt < 16; ++nt)
        #pragma unroll
        for (int ks = 0; ks < 3; ++ks) {
            const bf16x8 b = *(const bf16x8*)(Wcp + (size_t)(nt * 3 + ks) * 512 + lane * 8);
            acc[nt] = __builtin_amdgcn_mfma_f32_16x16x32_bf16(a[ks], b, acc[nt], 0, 0, 0);
        }

    // ---- stage P rows in LDS, coalesced ushort4 store (32 ushort4/row)
    #pragma unroll
    for (int nt = 0; nt < 8; ++nt)
        #pragma unroll
        for (int reg = 0; reg < 4; ++reg)
            s[wv * 16 + r * 4 + reg][nt * 16 + c] = f2bf(acc[nt][reg]);
    __syncthreads();
    {
        const int nl = tid >> 2, q = tid & 3;
        const int n = base + nl;
        if (n < N) {
            const ushort4* src = (const ushort4*)&s[nl][0];
            ushort4* dst = (ushort4*)(P + (size_t)n * 128);
            #pragma unroll
            for (int u = 0; u < 8; ++u) dst[q * 8 + u] = src[q * 8 + u];
        }
    }
    __syncthreads();

    // ---- stage Q rows, same path
    #pragma unroll
    for (int nt = 8; nt < 16; ++nt)
        #pragma unroll
        for (int reg = 0; reg < 4; ++reg)
            s[wv * 16 + r * 4 + reg][(nt - 8) * 16 + c] = f2bf(acc[nt][reg]);
    __syncthreads();
    {
        const int nl = tid >> 2, q = tid & 3;
        const int n = base + nl;
        if (n < N) {
            const ushort4* src = (const ushort4*)&s[nl][0];
            ushort4* dst = (ushort4*)(Q + (size_t)n * 128);
            #pragma unroll
            for (int u = 0; u < 8; ++u) dst[q * 8 + u] = src[q * 8 + u];
        }
    }
}

// ------- K4: relu(P[i]+Q[j]) -> layer-2 MFMA -> fused seg-reduce ----

__global__ __launch_bounds__(256) void edge_aggr_mfma(
    const unsigned short* __restrict__ P, const unsigned short* __restrict__ Q,
    const unsigned* __restrict__ eij,
    const unsigned short* __restrict__ W2p, const float* __restrict__ b2,
    float* __restrict__ aggr, int E)
{
    __shared__ unsigned short s_m[EPB][72];  // msgs, 64 cols + 8 pad
    __shared__ unsigned s_ij[EPB];           // packed (i<<16)|j
    __shared__ int  s_start[EPB + 4];        // run starts + terminator
    __shared__ int  s_wsumA[2];
    __shared__ int  s_nruns;

    const int tid  = threadIdx.x;
    const int wv   = tid >> 6;
    const int lane = tid & 63;
    const int r    = lane >> 4;
    const int c    = lane & 15;

    // XCD-contiguous swizzle: grid padded to x8
    const int per  = gridDim.x >> 3;
    const int swz  = (blockIdx.x & 7) * per + (blockIdx.x >> 3);
    const int base = swz * EPB;
    if (base >= E) return;
    const int ne   = min(EPB, E - base);     // valid slots in this block (>=1)

    if (tid < EPB) {
        const int p = base + tid;
        s_ij[tid] = eij[min(p, E - 1)];      // clamped: pad slots hold valid (i,j)
    }
    __syncthreads();

    // ---- layer-2 A-frags: relu(P[i]+Q[j]) via packed-dword unpack/add/trunc
    bf16x8 a2[2][4];
    #pragma unroll
    for (int mh = 0; mh < 2; ++mh) {
        const unsigned ij = s_ij[wv * 32 + mh * 16 + c];
        const unsigned* Pi = (const unsigned*)(P + (size_t)(ij >> 16) * 128);
        const unsigned* Qj = (const unsigned*)(Q + (size_t)(ij & 0xFFFFu) * 128);
        #pragma unroll
        for (int ks = 0; ks < 4; ++ks) {
            const uint4 pu = *(const uint4*)(Pi + ks * 16 + r * 4);
            const uint4 qu = *(const uint4*)(Qj + ks * 16 + r * 4);
            uint4 h;
            h.x = relu_add_pk(pu.x, qu.x);
            h.y = relu_add_pk(pu.y, qu.y);
            h.z = relu_add_pk(pu.z, qu.z);
            h.w = relu_add_pk(pu.w, qu.w);
            a2[mh][ks] = *(const bf16x8*)&h;
        }
    }

    // ---- layer 2: msg = hidden @ W2 + b2, N=64, K=128
    f32x4 acc2[2][4];
    #pragma unroll
    for (int nt = 0; nt < 4; ++nt) {
        const float bv = b2[nt * 16 + c];
        acc2[0][nt] = (f32x4){bv, bv, bv, bv};
        acc2[1][nt] = (f32x4){bv, bv, bv, bv};
    }
    #pragma unroll
    for (int nt = 0; nt < 4; ++nt)
        #pragma unroll
        for (int ks = 0; ks < 4; ++ks) {
            const bf16x8 b = *(const bf16x8*)(W2p + (size_t)(nt * 4 + ks) * 512 + lane * 8);
            acc2[0][nt] = __builtin_amdgcn_mfma_f32_16x16x32_bf16(a2[0][ks], b, acc2[0][nt], 0, 0, 0);
            acc2[1][nt] = __builtin_amdgcn_mfma_f32_16x16x32_bf16(a2[1][ks], b, acc2[1][nt], 0, 0, 0);
        }

    // ---- msgs to LDS (bf16, RNE)
    #pragma unroll
    for (int mh = 0; mh < 2; ++mh)
        #pragma unroll
        for (int nt = 0; nt < 4; ++nt)
            #pragma unroll
            for (int reg = 0; reg < 4; ++reg) {
                const int row = wv * 32 + mh * 16 + r * 4 + reg;
                s_m[row][nt * 16 + c] = f2bf(acc2[mh][nt][reg]);
            }

    // ---- run detection over slots [0, ne): compare high-16 (i field)
    int flag = 0, incl = 0;
    if (tid < EPB) {
        flag = (tid < ne) &&
               (tid == 0 || (s_ij[tid] >> 16) != (s_ij[tid - 1] >> 16));
        incl = flag;
    }
    #pragma unroll
    for (int d = 1; d < 64; d <<= 1) {
        int t = __shfl_up(incl, d, 64);
        if (lane >= d) incl += t;
    }
    if (tid < EPB && lane == 63) s_wsumA[tid >> 6] = incl;
    __syncthreads();                         // also covers s_m writes above
    if (tid < EPB) {
        const int rid = incl + ((tid >= 64) ? s_wsumA[0] : 0);
        if (flag) s_start[rid - 1] = tid;
    }
    if (tid == 0) {
        const int nr = s_wsumA[0] + s_wsumA[1];
        s_nruns = nr;
        s_start[nr] = ne;
    }
    __syncthreads();

    // ---- segmented reduce: one wave per run, lanes = 64 cols
    for (int rn = wv; rn < s_nruns; rn += 4) {
        const int e0 = s_start[rn], e1 = s_start[rn + 1];
        const int i  = (int)(s_ij[e0] >> 16);
        float acc = 0.f;
        for (int e = e0; e < e1; ++e)
            acc += bf2f(s_m[e][lane]);
        atomicAdd(&aggr[(size_t)i * 64 + lane], acc);
    }
}

// ---------------- K5: node MLP (streaming aggr) ----------------

__global__ __launch_bounds__(256) void node_mlp_mfma(
    const float* __restrict__ x, const float* __restrict__ aggr,
    const int* __restrict__ off,
    const unsigned short* __restrict__ W3p, const float* __restrict__ b3,
    const unsigned short* __restrict__ W4p, const float* __restrict__ b4,
    float* __restrict__ out, int N)
{
    __shared__ unsigned short s_a[NPB][136];  // 128 + 8 pad

    const int tid  = threadIdx.x;
    const int wv   = tid >> 6;
    const int lane = tid & 63;
    const int r    = lane >> 4;
    const int c    = lane & 15;
    const int base = blockIdx.x * NPB;

    for (int nl = wv; nl < NPB; nl += 4) {
        const int n = base + nl;
        if (n < N) {
            s_a[nl][lane] = f2bf(x[(size_t)n * 64 + lane]);
            const int deg = off[n + 1] - off[n];
            const float a = aggr[(size_t)n * 64 + lane] / (float)max(deg, 1);
            s_a[nl][64 + lane] = f2bf(a);
        } else {
            s_a[nl][lane] = 0;
            s_a[nl][64 + lane] = 0;
        }
    }
    __syncthreads();

    bf16x8 a1[4];
    #pragma unroll
    for (int ks = 0; ks < 4; ++ks)
        a1[ks] = *(const bf16x8*)&s_a[wv * 16 + c][ks * 32 + r * 8];
    __syncthreads();

    f32x4 acc1[8];
    #pragma unroll
    for (int nt = 0; nt < 8; ++nt) {
        const float bv = b3[nt * 16 + c];
        acc1[nt] = (f32x4){bv, bv, bv, bv};
    }
    #pragma unroll
    for (int nt = 0; nt < 8; ++nt)
        #pragma unroll
        for (int ks = 0; ks < 4; ++ks) {
            const bf16x8 b = *(const bf16x8*)(W3p + (size_t)(nt * 4 + ks) * 512 + lane * 8);
            acc1[nt] = __builtin_amdgcn_mfma_f32_16x16x32_bf16(a1[ks], b, acc1[nt], 0, 0, 0);
        }
    #pragma unroll
    for (int nt = 0; nt < 8; ++nt)
        #pragma unroll
        for (int reg = 0; reg < 4; ++reg)
            s_a[wv * 16 + r * 4 + reg][nt * 16 + c] = f2bf(fmaxf(acc1[nt][reg], 0.f));
    __syncthreads();

    bf16x8 a2[4];
    #pragma unroll
    for (int ks = 0; ks < 4; ++ks)
        a2[ks] = *(const bf16x8*)&s_a[wv * 16 + c][ks * 32 + r * 8];
    __syncthreads();

    f32x4 acc2[4];
    #pragma unroll
    for (int nt = 0; nt < 4; ++nt) {
        const float bv = b4[nt * 16 + c];
        acc2[nt] = (f32x4){bv, bv, bv, bv};
    }
    #pragma unroll
    for (int nt = 0; nt < 4; ++nt)
        #pragma unroll
        for (int ks = 0; ks < 4; ++ks) {
            const bf16x8 b = *(const bf16x8*)(W4p + (size_t)(nt * 4 + ks) * 512 + lane * 8);
            acc2[nt] = __builtin_amdgcn_mfma_f32_16x16x32_bf16(a2[ks], b, acc2[nt], 0, 0, 0);
        }

    #pragma unroll
    for (int nt = 0; nt < 4; ++nt)
        #pragma unroll
        for (int reg = 0; reg < 4; ++reg) {
            float* row = (float*)&s_a[wv * 16 + r * 4 + reg][0];
            row[nt * 16 + c] = acc2[nt][reg];
        }
    __syncthreads();

    {
        const int nl = tid >> 2, q = tid & 3;
        const int n = base + nl;
        if (n < N) {
            const float4* src = (const float4*)((const float*)&s_a[nl][0] + q * 16);
            float4* dst = (float4*)(out + (size_t)n * 64 + q * 16);
            #pragma unroll
            for (int u = 0; u < 4; ++u) dst[u] = src[u];
        }
    }
}

// ---------------- fallback (atomic fp32 path, if ws too small) ----------------

#define EB 32
#define NB 32

__global__ __launch_bounds__(256) void mpnn_edge_atomic_kernel(
    const float* __restrict__ x, const float* __restrict__ pos,
    const int* __restrict__ ei0, const int* __restrict__ ei1,
    const float* __restrict__ W1, const float* __restrict__ b1,
    const float* __restrict__ W2, const float* __restrict__ b2,
    float* __restrict__ summed, float* __restrict__ counts, int E)
{
    __shared__ float s_in[EB][132];
    __shared__ int   s_idx[EB];

    const int tid  = threadIdx.x;
    const int base = blockIdx.x * EB;
    const int wv   = tid >> 6;
    const int lane = tid & 63;

    for (int e = wv; e < EB; e += 4) {
        const int ei = base + e;
        if (ei < E) {
            const int i = ei0[ei];
            const int j = ei1[ei];
            const float xi = x[(size_t)i * 64 + lane];
            const float xj = x[(size_t)j * 64 + lane];
            s_in[e][lane]      = xi;
            s_in[e][64 + lane] = xj - xi;
            if (lane < 3)
                s_in[e][128 + lane] = pos[(size_t)j * 3 + lane] - pos[(size_t)i * 3 + lane];
            if (lane == 0) s_idx[e] = i;
        } else {
            s_in[e][lane] = 0.f; s_in[e][64 + lane] = 0.f;
            if (lane < 3) s_in[e][128 + lane] = 0.f;
            if (lane == 0) s_idx[e] = -1;
        }
    }
    __syncthreads();

    float acc1[4][4];
    {
        const int cg = tid & 31;
        const int er = tid >> 5;
        const float4 bb = *(const float4*)(b1 + 4 * cg);
        #pragma unroll
        for (int t = 0; t < 4; ++t) {
            acc1[t][0] = bb.x; acc1[t][1] = bb.y; acc1[t][2] = bb.z; acc1[t][3] = bb.w;
        }
        for (int k = 0; k < 128; k += 4) {
            float wv4[4][4];
            #pragma unroll
            for (int kk = 0; kk < 4; ++kk) {
                const float4 w = *(const float4*)(W1 + (size_t)(k + kk) * 128 + 4 * cg);
                wv4[kk][0] = w.x; wv4[kk][1] = w.y; wv4[kk][2] = w.z; wv4[kk][3] = w.w;
            }
            #pragma unroll
            for (int t = 0; t < 4; ++t) {
                const float4 m = *(const float4*)(&s_in[er + 8 * t][k]);
                const float mm[4] = {m.x, m.y, m.z, m.w};
                #pragma unroll
                for (int kk = 0; kk < 4; ++kk)
                    #pragma unroll
                    for (int cc = 0; cc < 4; ++cc)
                        acc1[t][cc] += mm[kk] * wv4[kk][cc];
            }
        }
        for (int k = 128; k < 131; ++k) {
            float wk[4];
            #pragma unroll
            for (int cc = 0; cc < 4; ++cc) wk[cc] = W1[(size_t)k * 128 + 4 * cg + cc];
            #pragma unroll
            for (int t = 0; t < 4; ++t) {
                const float m = s_in[er + 8 * t][k];
                #pragma unroll
                for (int cc = 0; cc < 4; ++cc) acc1[t][cc] += m * wk[cc];
            }
        }
    }
    __syncthreads();
    {
        const int cg = tid & 31;
        const int er = tid >> 5;
        #pragma unroll
        for (int t = 0; t < 4; ++t)
            #pragma unroll
            for (int cc = 0; cc < 4; ++cc)
                s_in[er + 8 * t][4 * cg + cc] = fmaxf(acc1[t][cc], 0.f);
    }
    __syncthreads();
    {
        const int cg = tid & 15;
        const int er = tid >> 4;
        float acc[2][4];
        const float4 bb = *(const float4*)(b2 + 4 * cg);
        #pragma unroll
        for (int t = 0; t < 2; ++t) {
            acc[t][0] = bb.x; acc[t][1] = bb.y; acc[t][2] = bb.z; acc[t][3] = bb.w;
        }
        for (int k = 0; k < 128; k += 4) {
            float wv4[4][4];
            #pragma unroll
            for (int kk = 0; kk < 4; ++kk) {
                const float4 w = *(const float4*)(W2 + (size_t)(k + kk) * 64 + 4 * cg);
                wv4[kk][0] = w.x; wv4[kk][1] = w.y; wv4[kk][2] = w.z; wv4[kk][3] = w.w;
            }
            #pragma unroll
            for (int t = 0; t < 2; ++t) {
                const float4 m = *(const float4*)(&s_in[er + 16 * t][k]);
                const float mm[4] = {m.x, m.y, m.z, m.w};
                #pragma unroll
                for (int kk = 0; kk < 4; ++kk)
                    #pragma unroll
                    for (int cc = 0; cc < 4; ++cc)
                        acc[t][cc] += mm[kk] * wv4[kk][cc];
            }
        }
        #pragma unroll
        for (int t = 0; t < 2; ++t) {
            const int e = er + 16 * t;
            const int i = s_idx[e];
            if (i >= 0) {
                #pragma unroll
                for (int cc = 0; cc < 4; ++cc)
                    atomicAdd(&summed[(size_t)i * 64 + 4 * cg + cc], acc[t][cc]);
            }
        }
    }
    if (tid < EB) {
        const int i = s_idx[tid];
        if (i >= 0) atomicAdd(&counts[i], 1.0f);
    }
}

__global__ __launch_bounds__(256) void mpnn_node_legacy_kernel(
    const float* __restrict__ x, const float* __restrict__ summed,
    const float* __restrict__ counts,
    const float* __restrict__ W3, const float* __restrict__ b3,
    const float* __restrict__ W4, const float* __restrict__ b4,
    float* __restrict__ out, int N)
{
    __shared__ float s_in[NB][132];

    const int tid  = threadIdx.x;
    const int base = blockIdx.x * NB;
    const int wv   = tid >> 6;
    const int lane = tid & 63;

    for (int nl = wv; nl < NB; nl += 4) {
        const int n = base + nl;
        if (n < N) {
            s_in[nl][lane] = x[(size_t)n * 64 + lane];
            const float inv = 1.0f / fmaxf(counts[n], 1.0f);
            s_in[nl][64 + lane] = summed[(size_t)n * 64 + lane] * inv;
        } else {
            s_in[nl][lane] = 0.f; s_in[nl][64 + lane] = 0.f;
        }
    }
    __syncthreads();

    float acc1[4][4];
    {
        const int cg = tid & 31;
        const int er = tid >> 5;
        const float4 bb = *(const float4*)(b3 + 4 * cg);
        #pragma unroll
        for (int t = 0; t < 4; ++t) {
            acc1[t][0] = bb.x; acc1[t][1] = bb.y; acc1[t][2] = bb.z; acc1[t][3] = bb.w;
        }
        for (int k = 0; k < 128; k += 4) {
            float wv4[4][4];
            #pragma unroll
            for (int kk = 0; kk < 4; ++kk) {
                const float4 w = *(const float4*)(W3 + (size_t)(k + kk) * 128 + 4 * cg);
                wv4[kk][0] = w.x; wv4[kk][1] = w.y; wv4[kk][2] = w.z; wv4[kk][3] = w.w;
            }
            #pragma unroll
            for (int t = 0; t < 4; ++t) {
                const float4 m = *(const float4*)(&s_in[er + 8 * t][k]);
                const float mm[4] = {m.x, m.y, m.z, m.w};
                #pragma unroll
                for (int kk = 0; kk < 4; ++kk)
                    #pragma unroll
                    for (int cc = 0; cc < 4; ++cc)
                        acc1[t][cc] += mm[kk] * wv4[kk][cc];
            }
        }
    }
    __syncthreads();
    {
        const int cg = tid & 31;
        const int er = tid >> 5;
        #pragma unroll
        for (int t = 0; t < 4; ++t)
            #pragma unroll
            for (int cc = 0; cc < 4; ++cc)
                s_in[er + 8 * t][4 * cg + cc] = fmaxf(acc1[t][cc], 0.f);
    }
    __syncthreads();
    {
        const int cg = tid & 15;
        const int er = tid >> 4;
        float acc[2][4];
        const float4 bb = *(const float4*)(b4 + 4 * cg);
        #pragma unroll
        for (int t = 0; t < 2; ++t) {
            acc[t][0] = bb.x; acc[t][1] = bb.y; acc[t][2] = bb.z; acc[t][3] = bb.w;
        }
        for (int k = 0; k < 128; k += 4) {
            float wv4[4][4];
            #pragma unroll
            for (int kk = 0; kk < 4; ++kk) {
                const float4 w = *(const float4*)(W4 + (size_t)(k + kk) * 64 + 4 * cg);
                wv4[kk][0] = w.x; wv4[kk][1] = w.y; wv4[kk][2] = w.z; wv4[kk][3] = w.w;
            }
            #pragma unroll
            for (int t = 0; t < 2; ++t) {
                const float4 m = *(const float4*)(&s_in[er + 16 * t][k]);
                const float mm[4] = {m.x, m.y, m.z, m.w};
                #pragma unroll
                for (int kk = 0; kk < 4; ++kk)
                    #pragma unroll
                    for (int cc = 0; cc < 4; ++cc)
                        acc[t][cc] += mm[kk] * wv4[kk][cc];
            }
        }
        #pragma unroll
        for (int t = 0; t < 2; ++t) {
            const int n = base + er + 16 * t;
            if (n < N) {
                float4 o;
                o.x = acc[t][0]; o.y = acc[t][1]; o.z = acc[t][2]; o.w = acc[t][3];
                *(float4*)(out + (size_t)n * 64 + 4 * cg) = o;
            }
        }
    }
}

// ---------------- launch ----------------

static inline size_t rup(size_t v) { return (v + 255) & ~(size_t)255; }

extern "C" void kernel_launch(void* const* d_in, const int* in_sizes, int n_in,
                              void* d_out, int out_size, void* d_ws, size_t ws_size,
                              hipStream_t stream) {
    const float* x    = (const float*)d_in[0];
    const float* pos  = (const float*)d_in[1];
    const int*   eidx = (const int*)d_in[2];
    const float* W1   = (const float*)d_in[3];
    const float* b1   = (const float*)d_in[4];
    const float* W2   = (const float*)d_in[5];
    const float* b2   = (const float*)d_in[6];
    const float* W3   = (const float*)d_in[7];
    const float* b3   = (const float*)d_in[8];
    const float* W4   = (const float*)d_in[9];
    const float* b4   = (const float*)d_in[10];

    const int N = in_sizes[0] / 64;
    const int E = in_sizes[2] / 2;
    const int* ei0 = eidx;       // edge_index[0] = aggregation node i
    const int* ei1 = eidx + E;   // edge_index[1] = neighbor j

    const size_t p_b    = rup((size_t)N * 128 * 2);
    const size_t q_b    = rup((size_t)N * 128 * 2);
    const size_t wcp_b  = rup(48 * 512 * 2);
    const size_t w2p_b  = rup(16 * 512 * 2);
    const size_t w3p_b  = rup(32 * 512 * 2);
    const size_t w4p_b  = rup(16 * 512 * 2);
    const size_t aggr_b = rup((size_t)N * 64 * 4);
    const size_t cnt_b  = rup((size_t)N * 4);
    const size_t off_b  = rup((size_t)(N + 1) * 4);
    const size_t bsum_b = rup(256 * 4);
    const size_t rank_b = rup((size_t)E * 4);
    const size_t eij_b  = rup((size_t)E * 4);   // packed u32
    const size_t need = p_b + q_b + wcp_b + w2p_b + w3p_b + w4p_b +
                        aggr_b + cnt_b + off_b + bsum_b + rank_b + eij_b;

    if (ws_size >= need && N < 65536) {
        char* p = (char*)d_ws;
        unsigned short* P   = (unsigned short*)p;  p += p_b;
        unsigned short* Q   = (unsigned short*)p;  p += q_b;
        unsigned short* Wcp = (unsigned short*)p;  p += wcp_b;
        unsigned short* W2p = (unsigned short*)p;  p += w2p_b;
        unsigned short* W3p = (unsigned short*)p;  p += w3p_b;
        unsigned short* W4p = (unsigned short*)p;  p += w4p_b;
        float* aggr = (float*)p;  p += aggr_b;
        int* cnt  = (int*)p;  p += cnt_b;
        int* off  = (int*)p;  p += off_b;
        int* bsum = (int*)p;  p += bsum_b;
        int* rank = (int*)p;  p += rank_b;
        unsigned* eij = (unsigned*)p;

        // zero aggr + cnt in one memset (adjacent; ~3us measured at R11)
        hipMemsetAsync(aggr, 0, aggr_b + cnt_b, stream);

        // K1: pack (28 blocks) U count(+rank) U bsum sentinels
        const int cntBlocks = (E + 255) / 256;
        prep_kernel<<<28 + cntBlocks, 256, 0, stream>>>(
            W1, W2, W3, W4, Wcp, W2p, W3p, W4p, ei0, cnt, rank, bsum, E);

        // K2: lookback scan (alone; 196 blocks, co-resident)
        const int scanBlocks = (N + 255) / 256;
        scan_kernel<<<scanBlocks, 256, 0, stream>>>(cnt, bsum, off, N, E);

        // K3: fill (3125 blocks, first) U pq (782 blocks)
        const int fillBlocks = (E + 255) / 256;
        const int pqBlocks   = (N + NPB - 1) / NPB;
        fill_pq_kernel<<<fillBlocks + pqBlocks, 256, 0, stream>>>(
            ei0, ei1, off, rank, eij, x, pos, Wcp, b1, P, Q, N, E, fillBlocks);

        // K4: edge (256 threads, grid padded to x8 for XCD-contiguous swizzle)
        const int edgeBlocks = ((E + EPB - 1) / EPB + 7) & ~7;
        edge_aggr_mfma<<<edgeBlocks, 256, 0, stream>>>(
            P, Q, eij, W2p, b2, aggr, E);

        // K5: node
        node_mlp_mfma<<<pqBlocks, 256, 0, stream>>>(
            x, aggr, off, W3p, b3, W4p, b4, (float*)d_out, N);
    } else {
        // fallback: atomic fp32 path
        float* summed = (float*)d_ws;
        float* counts = summed + (size_t)N * 64;
        hipMemsetAsync(d_ws, 0, ((size_t)N * 64 + N) * sizeof(float), stream);

        mpnn_edge_atomic_kernel<<<(E + EB - 1) / EB, 256, 0, stream>>>(
            x, pos, ei0, ei1, W1, b1, W2, b2, summed, counts, E);
        mpnn_node_legacy_kernel<<<(N + NB - 1) / NB, 256, 0, stream>>>(
            x, summed, counts, W3, b3, W4, b4, (float*)d_out, N);
    }
}